// Round 17
// baseline (242.615 us; speedup 1.0000x reference)
//
#include <hip/hip_runtime.h>
#include <hip/hip_bf16.h>

// DiagWinAttention: nw=4096, N=64 tokens, E=96 = 6 heads x 16. fp32 I/O.
// R17: fully wave-independent decomposition -- ZERO __syncthreads.
// Block = 256 thr = 4 waves = 1 window; wave owns a 16-row tile across all
// 6 heads (head loop). Swapped QK^T (R9 math, rt == wave id), in-register
// softmax with late normalization, X in a per-wave private LDS strip,
// wave-local LN (row=l15, quarter=g, 2 shfl_xor), proj as Y^T =
// mfma(W-frag, Xn-B-frag), per-wave staged output + coalesced copy of the
// wave's contiguous 6KB row range. Only wave-local lgkmcnt fences.
// Mask read once per wave (its own 16 rows). K/V re-read per wave: L2-hot.
// (256,5) -> unified cap 102, demand ~75: no spill. Tripwire: WRITE==98304.

typedef short v4s __attribute__((ext_vector_type(4)));
typedef float v4f __attribute__((ext_vector_type(4)));

#define MFMA16(A, B, C) __builtin_amdgcn_mfma_f32_16x16x16bf16_1k(A, B, C, 0, 0, 0)

static __device__ __forceinline__ ushort f2b(float x) {
  union { __hip_bfloat16 h; ushort u; } c; c.h = __float2bfloat16(x); return c.u;
}
static __device__ __forceinline__ float b2f(ushort u) {
  union { ushort u; __hip_bfloat16 h; } c; c.u = u; return __bfloat162float(c.h);
}

#define SXW 100     // per-wave X strip stride (ushort); 16 rows = 3200 B
#define SYW 99      // per-wave Y strip stride (fp32, odd -> spread banks)
#define LOG2E 1.4426950408889634f
#define WAVE_SYNC() asm volatile("s_waitcnt lgkmcnt(0)" ::: "memory")

__global__ __launch_bounds__(256, 5)
void winattn_kernel(const float* __restrict__ gQ, const float* __restrict__ gK,
                    const float* __restrict__ gV, const float* __restrict__ gM,
                    const float* __restrict__ gBT, const float* __restrict__ gGa,
                    const float* __restrict__ gBe, const float* __restrict__ gW,
                    const float* __restrict__ gPb, float* __restrict__ gO)
{
  // 4 private 6400-B wave regions: X (bf16, 16xSXW) then Y overlay (fp32, 16xSYW)
  __shared__ __align__(16) char smem[4 * 6400];

  const int tid  = threadIdx.x;
  const int wid  = tid >> 6;          // wave = row-tile 0..3
  const int lane = tid & 63;
  const int l15  = lane & 15;
  const int g    = lane >> 4;
  const int w    = blockIdx.x;
  const size_t base = (size_t)w * 6144;

  ushort* sXw = (ushort*)(smem + wid * 6400);
  float*  sYw = (float*)(smem + wid * 6400);

  // ---- this wave's 16 mask rows, kept in 16 regs (read once) ----
  float4 mv[4];
  {
    const float4* m4f = (const float4*)(gM + (size_t)w * 4096);
    #pragma unroll
    for (int ct = 0; ct < 4; ++ct)
      mv[ct] = m4f[(16 * wid + l15) * 16 + 4 * ct + g];
  }
  const int bb = ((l15 >> 3) - (g >> 1)) * 15 + (l15 & 7) - 4 * (g & 1) + 112;

  // ================= head loop: QK^T -> softmax -> PV -> X strip ===========
  #pragma unroll 1
  for (int h = 0; h < 6; ++h) {
    // A-frag: this wave's 16 Q rows (scale*log2e folded)
    v4s aq;
    {
      const float QS = 0.25f * LOG2E;
      float4 qv = *(const float4*)(gQ + base + (16 * wid + l15) * 96 + 16 * h + 4 * g);
      v4s a; a[0] = (short)f2b(qv.x * QS); a[1] = (short)f2b(qv.y * QS);
      a[2] = (short)f2b(qv.z * QS); a[3] = (short)f2b(qv.w * QS);
      aq = a;
    }
    // K frags: all 64 rows (A-operand of swapped QK^T)
    v4s bk[4];
    #pragma unroll
    for (int t = 0; t < 4; ++t) {
      float4 kv = *(const float4*)(gK + base + (16 * t + l15) * 96 + 16 * h + 4 * g);
      v4s b; b[0] = (short)f2b(kv.x); b[1] = (short)f2b(kv.y);
      b[2] = (short)f2b(kv.z); b[3] = (short)f2b(kv.w);
      bk[t] = b;
    }
    // V frags: all 64 rows (B-operand of PV)
    v4s vf[4];
    {
      const float* vp = gV + base + 16 * h + l15;
      #pragma unroll
      for (int kk = 0; kk < 4; ++kk) {
        float a0 = vp[(16 * kk + 4 * g + 0) * 96];
        float a1 = vp[(16 * kk + 4 * g + 1) * 96];
        float a2 = vp[(16 * kk + 4 * g + 2) * 96];
        float a3 = vp[(16 * kk + 4 * g + 3) * 96];
        v4s t; t[0] = (short)f2b(a0); t[1] = (short)f2b(a1);
        t[2] = (short)f2b(a2); t[3] = (short)f2b(a3);
        vf[kk] = t;
      }
    }

    // serial ct: QK^T -> exp2 -> unnormalized bf16 pa; r applied after PV
    float s = 0.f;
    v4s pa[4];
    #pragma unroll
    for (int ct = 0; ct < 4; ++ct) {
      float bv0 = gBT[(bb + 30 * (wid - ct) - 0) * 6 + h];
      float bv1 = gBT[(bb + 30 * (wid - ct) - 1) * 6 + h];
      float bv2 = gBT[(bb + 30 * (wid - ct) - 2) * 6 + h];
      float bv3 = gBT[(bb + 30 * (wid - ct) - 3) * 6 + h];
      v4f acc = {mv[ct].x * LOG2E + bv0 * LOG2E,
                 mv[ct].y * LOG2E + bv1 * LOG2E,
                 mv[ct].z * LOG2E + bv2 * LOG2E,
                 mv[ct].w * LOG2E + bv3 * LOG2E};
      acc = MFMA16(bk[ct], aq, acc);
      float e0 = exp2f(acc[0]);
      float e1 = exp2f(acc[1]);
      float e2 = exp2f(acc[2]);
      float e3 = exp2f(acc[3]);
      s += (e0 + e1) + (e2 + e3);
      v4s t;
      t[0] = (short)f2b(e0); t[1] = (short)f2b(e1);
      t[2] = (short)f2b(e2); t[3] = (short)f2b(e3);
      pa[ct] = t;
    }
    s += __shfl_xor(s, 16, 64);
    s += __shfl_xor(s, 32, 64);
    const float r = __builtin_amdgcn_rcpf(s);   // row = 16*wid + l15

    v4f oa = {0.f, 0.f, 0.f, 0.f};
    #pragma unroll
    for (int ct = 0; ct < 4; ++ct) oa = MFMA16(pa[ct], vf[ct], oa);

    // O local row lr = 4g+rg, col = 16h+l15; r comes from lane (4g+rg)
    const float* qrp = gQ + base + (16 * wid) * 96 + 16 * h + l15;
    #pragma unroll
    for (int rg = 0; rg < 4; ++rg) {
      const float rr = __shfl(r, 4 * g + rg, 64);
      const int lr = 4 * g + rg;
      sXw[lr * SXW + 16 * h + l15] = f2b(oa[rg] * rr + 0.25f * qrp[lr * 96]);
    }
  }
  WAVE_SYNC();                                   // X strip visible wave-locally

  // ================= wave-local LayerNorm: row = l15, quarter = g ==========
  {
    ushort* xr = &sXw[l15 * SXW + 24 * g];
    float x[24];
    #pragma unroll
    for (int i = 0; i < 6; ++i) {
      ushort4 u = *(const ushort4*)&xr[i * 4];
      x[4 * i + 0] = b2f(u.x); x[4 * i + 1] = b2f(u.y);
      x[4 * i + 2] = b2f(u.z); x[4 * i + 3] = b2f(u.w);
    }
    float s1 = 0.f, s2 = 0.f;
    #pragma unroll
    for (int i = 0; i < 24; ++i) { s1 += x[i]; s2 += x[i] * x[i]; }
    s1 += __shfl_xor(s1, 16, 64); s2 += __shfl_xor(s2, 16, 64);
    s1 += __shfl_xor(s1, 32, 64); s2 += __shfl_xor(s2, 32, 64);
    const float mu  = s1 * (1.f / 96.f);
    const float var = s2 * (1.f / 96.f) - mu * mu;
    const float rsig = __builtin_amdgcn_rsqf(var + 1e-5f);
    #pragma unroll
    for (int i = 0; i < 6; ++i) {
      float4 gv = *(const float4*)(gGa + 24 * g + 4 * i);
      float4 bv = *(const float4*)(gBe + 24 * g + 4 * i);
      ushort4 o;
      o.x = f2b((x[4 * i + 0] - mu) * rsig * gv.x + bv.x);
      o.y = f2b((x[4 * i + 1] - mu) * rsig * gv.y + bv.y);
      o.z = f2b((x[4 * i + 2] - mu) * rsig * gv.z + bv.z);
      o.w = f2b((x[4 * i + 3] - mu) * rsig * gv.w + bv.w);
      *(ushort4*)&xr[i * 4] = o;
    }
  }
  WAVE_SYNC();                                   // Xn visible wave-locally

  // ================= Xn B-frags into regs (strip then dead) ================
  v4s xb[6];
  #pragma unroll
  for (int kk = 0; kk < 6; ++kk)
    xb[kk] = *(const v4s*)&sXw[l15 * SXW + 16 * kk + 4 * g];
  WAVE_SYNC();                                   // reads ordered before Y overlay

  // ================= projection: Y^T = W-frag x Xn-frag, staged out ========
  #pragma unroll
  for (int ot = 0; ot < 6; ++ot) {
    v4s wfr[6];
    #pragma unroll
    for (int kk = 0; kk < 6; ++kk) {
      float4 wv = *(const float4*)(gW + (16 * ot + l15) * 96 + 16 * kk + 4 * g);
      v4s t; t[0] = (short)f2b(wv.x); t[1] = (short)f2b(wv.y);
      t[2] = (short)f2b(wv.z); t[3] = (short)f2b(wv.w);
      wfr[kk] = t;
    }
    float4 pb4 = *(const float4*)(gPb + 16 * ot + 4 * g);
    v4f ya = {0.f, 0.f, 0.f, 0.f};
    #pragma unroll
    for (int kk = 0; kk < 6; ++kk) ya = MFMA16(wfr[kk], xb[kk], ya);
    // D: col = l15 = q-row (local), row = 4g+rg = output channel 16*ot+4g+rg
    const float pbv[4] = {pb4.x, pb4.y, pb4.z, pb4.w};
    #pragma unroll
    for (int rg = 0; rg < 4; ++rg)
      sYw[l15 * SYW + 16 * ot + 4 * g + rg] = ya[rg] + pbv[rg];
  }
  WAVE_SYNC();                                   // Y strip complete

  // ---- coalesced copy: wave's contiguous 16 rows x 96 fp32 (6 KB) ----
  float4* o4 = (float4*)(gO + base + (size_t)wid * 1536);
  #pragma unroll
  for (int i = 0; i < 6; ++i) {
    const int idx = lane + 64 * i;               // 384 float4 = 16 rows x 24
    const int r = idx / 24, c = idx % 24;
    o4[idx] = *(const float4*)&sYw[r * SYW + c * 4];
  }
}

extern "C" void kernel_launch(void* const* d_in, const int* in_sizes, int n_in,
                              void* d_out, int out_size, void* d_ws, size_t ws_size,
                              hipStream_t stream) {
  (void)in_sizes; (void)n_in; (void)out_size; (void)d_ws; (void)ws_size;
  winattn_kernel<<<dim3(4096), dim3(256), 0, stream>>>(
      (const float*)d_in[0], (const float*)d_in[1], (const float*)d_in[2],
      (const float*)d_in[3], (const float*)d_in[4], (const float*)d_in[5],
      (const float*)d_in[6], (const float*)d_in[7], (const float*)d_in[8],
      (float*)d_out);
}